// Round 1
// baseline (1068.694 us; speedup 1.0000x reference)
//
#include <hip/hip_runtime.h>
#include <math.h>

#define N 8192
#define D 64

// ---------------------------------------------------------------------------
// K1: Q = (X @ Wq) * 0.125 (scale folded in), K = X @ Wk, for both x and y.
// Rows 0..8191 -> x, 8192..16383 -> y. 16 rows/block.
// ---------------------------------------------------------------------------
__global__ __launch_bounds__(256) void proj_kernel(
    const float* __restrict__ Wq, const float* __restrict__ Wk,
    const float* __restrict__ X, const float* __restrict__ Y,
    float* __restrict__ Qx, float* __restrict__ Kx,
    float* __restrict__ Qy, float* __restrict__ Ky)
{
    __shared__ float sWq[64][64];
    __shared__ float sWk[64][64];
    __shared__ float sIn[16][64];
    const int t = threadIdx.x;
#pragma unroll
    for (int p = 0; p < 16; ++p) {
        int idx = p * 256 + t;
        sWq[idx >> 6][idx & 63] = Wq[idx];
        sWk[idx >> 6][idx & 63] = Wk[idx];
    }
    const int R0 = blockIdx.x * 16;
    const float* src; float* dq; float* dk; int r0;
    if (R0 < N) { src = X; dq = Qx; dk = Kx; r0 = R0; }
    else        { src = Y; dq = Qy; dk = Ky; r0 = R0 - N; }
#pragma unroll
    for (int p = 0; p < 4; ++p) {
        int idx = p * 256 + t;
        sIn[idx >> 6][idx & 63] = src[r0 * D + idx];
    }
    __syncthreads();
    const int c = t & 63;
    const int rb = t >> 6;
#pragma unroll
    for (int rr = 0; rr < 4; ++rr) {
        int r = rr * 4 + rb;
        float aq = 0.f, ak = 0.f;
#pragma unroll
        for (int k = 0; k < 64; ++k) {
            float xv = sIn[r][k];
            aq = fmaf(xv, sWq[k][c], aq);
            ak = fmaf(xv, sWk[k][c], ak);
        }
        dq[(r0 + r) * D + c] = aq * 0.125f;  // 1/sqrt(64) folded into Q
        dk[(r0 + r) * D + c] = ak;
    }
}

// ---------------------------------------------------------------------------
// K2: flash attention, fp32 vector. 64 query rows/block, KV tiles of 64.
// Thread grid 16x16; each thread owns a 4(row)x4(col/dim) register tile.
// LDS: QT[k][r] (staged once), sKP = KT[k][c] in S-phase then PT[c][r]
// after softmax (phase-separated reuse), sZ[c][d].
// grid = (128, 2): y==0 -> x side, y==1 -> y side.
// Epilogue also writes squared row norms of the attention output.
// ---------------------------------------------------------------------------
__global__ __launch_bounds__(256) void attn_kernel(
    const float* __restrict__ Qx, const float* __restrict__ Kx,
    const float* __restrict__ Qy, const float* __restrict__ Ky,
    const float* __restrict__ Xg, const float* __restrict__ Yg,
    float* __restrict__ OAx, float* __restrict__ OAy,
    float* __restrict__ n2x, float* __restrict__ n2y)
{
    __shared__ float sQT[64][64];   // [k][r]
    __shared__ float sKP[64][68];   // KT [k][c] -> PT [c][r]
    __shared__ float sZ[64][64];    // [c][d]
    const float *Q, *K, *Z;
    float *OA, *n2;
    if (blockIdx.y == 0) { Q = Qx; K = Kx; Z = Xg; OA = OAx; n2 = n2x; }
    else                 { Q = Qy; K = Ky; Z = Yg; OA = OAy; n2 = n2y; }
    const int t  = threadIdx.x;
    const int tr = t >> 4;          // 0..15 -> rows tr*4..tr*4+3
    const int tc = t & 15;          // 0..15 -> cols/dims tc*4..tc*4+3
    const int R0 = blockIdx.x * 64;

    // stage Q transposed (once per block; column writes conflict but amortized)
#pragma unroll
    for (int p = 0; p < 16; ++p) {
        int idx = p * 256 + t;
        int r = idx >> 6, k = idx & 63;
        sQT[k][r] = Q[(R0 + r) * D + k];
    }

    float acc[4][4];
    float m_i[4], l_i[4];
#pragma unroll
    for (int i = 0; i < 4; ++i) {
        m_i[i] = -INFINITY; l_i[i] = 0.f;
#pragma unroll
        for (int j = 0; j < 4; ++j) acc[i][j] = 0.f;
    }

    for (int tile = 0; tile < N / 64; ++tile) {
        const int base = tile * 64;
        __syncthreads();   // protect sKP/sZ vs previous PV reads
#pragma unroll
        for (int p = 0; p < 4; ++p) {
            int idx4 = p * 256 + t;
            int cc = idx4 >> 4;
            int k0 = (idx4 & 15) << 2;
            float4 kv = *(const float4*)&K[(base + cc) * D + k0];
            sKP[k0 + 0][cc] = kv.x;
            sKP[k0 + 1][cc] = kv.y;
            sKP[k0 + 2][cc] = kv.z;
            sKP[k0 + 3][cc] = kv.w;
            *(float4*)&sZ[cc][k0] = *(const float4*)&Z[(base + cc) * D + k0];
        }
        __syncthreads();

        // ----- S = Q K^T (Q pre-scaled by 1/8) -----
        float s[4][4];
#pragma unroll
        for (int i = 0; i < 4; ++i)
#pragma unroll
            for (int j = 0; j < 4; ++j) s[i][j] = 0.f;
        for (int k = 0; k < 64; ++k) {
            float qv[4], kv[4];
            *(float4*)qv = *(const float4*)&sQT[k][tr * 4];
            *(float4*)kv = *(const float4*)&sKP[k][tc * 4];
#pragma unroll
            for (int i = 0; i < 4; ++i)
#pragma unroll
                for (int j = 0; j < 4; ++j)
                    s[i][j] = fmaf(qv[i], kv[j], s[i][j]);
        }

        // ----- online softmax (row groups are 16 contiguous lanes) -----
#pragma unroll
        for (int i = 0; i < 4; ++i) {
            float mx = fmaxf(fmaxf(s[i][0], s[i][1]), fmaxf(s[i][2], s[i][3]));
#pragma unroll
            for (int off = 1; off < 16; off <<= 1)
                mx = fmaxf(mx, __shfl_xor(mx, off));
            float mn = fmaxf(m_i[i], mx);
            float al = __expf(m_i[i] - mn);   // 0 on first tile (m = -inf)
            float rs = 0.f;
#pragma unroll
            for (int j = 0; j < 4; ++j) {
                s[i][j] = __expf(s[i][j] - mn);
                rs += s[i][j];
            }
#pragma unroll
            for (int off = 1; off < 16; off <<= 1)
                rs += __shfl_xor(rs, off);
            l_i[i] = l_i[i] * al + rs;
            m_i[i] = mn;
#pragma unroll
            for (int j = 0; j < 4; ++j) acc[i][j] *= al;
        }
        __syncthreads();   // all S-phase reads of sKP done

        // write P transposed: PT[c][r]
#pragma unroll
        for (int j = 0; j < 4; ++j) {
            float4 pv = make_float4(s[0][j], s[1][j], s[2][j], s[3][j]);
            *(float4*)&sKP[tc * 4 + j][tr * 4] = pv;
        }
        __syncthreads();

        // ----- O += P Z -----
        for (int cc = 0; cc < 64; ++cc) {
            float pf[4], zf[4];
            *(float4*)pf = *(const float4*)&sKP[cc][tr * 4];
            *(float4*)zf = *(const float4*)&sZ[cc][tc * 4];
#pragma unroll
            for (int i = 0; i < 4; ++i)
#pragma unroll
                for (int j = 0; j < 4; ++j)
                    acc[i][j] = fmaf(pf[i], zf[j], acc[i][j]);
        }
    }

    // ----- epilogue: normalize, store attention output + row norms -----
    float sq[4];
#pragma unroll
    for (int i = 0; i < 4; ++i) {
        float inv = 1.f / l_i[i];
        float o[4];
#pragma unroll
        for (int j = 0; j < 4; ++j) o[j] = acc[i][j] * inv;
        *(float4*)&OA[(R0 + tr * 4 + i) * D + tc * 4] = *(float4*)o;
        sq[i] = o[0]*o[0] + o[1]*o[1] + o[2]*o[2] + o[3]*o[3];
    }
#pragma unroll
    for (int i = 0; i < 4; ++i) {
#pragma unroll
        for (int off = 1; off < 16; off <<= 1)
            sq[i] += __shfl_xor(sq[i], off);
    }
    if (tc == 0) {
#pragma unroll
        for (int i = 0; i < 4; ++i) n2[R0 + tr * 4 + i] = sq[i];
    }
}

// ---------------------------------------------------------------------------
// K3: RBF output tile. out[i][j] = exp(2*dot(xa_i, ya_j) - |xa_i|^2 - |ya_j|^2)
// 64x64 tile per block, 4x4 per thread. grid = (128 cols, 128 rows).
// ---------------------------------------------------------------------------
__global__ __launch_bounds__(256) void rbf_kernel(
    const float* __restrict__ XA, const float* __restrict__ YA,
    const float* __restrict__ n2x, const float* __restrict__ n2y,
    float* __restrict__ out)
{
    __shared__ float sXT[64][68];   // [k][r]
    __shared__ float sYT[64][68];   // [k][c]
    const int t  = threadIdx.x;
    const int tr = t >> 4, tc = t & 15;
    const int R0 = blockIdx.y * 64;   // x rows
    const int C0 = blockIdx.x * 64;   // y rows (output cols)
#pragma unroll
    for (int p = 0; p < 4; ++p) {
        int idx4 = p * 256 + t;
        int r  = idx4 >> 4;
        int k0 = (idx4 & 15) << 2;
        float4 xv = *(const float4*)&XA[(R0 + r) * D + k0];
        sXT[k0 + 0][r] = xv.x; sXT[k0 + 1][r] = xv.y;
        sXT[k0 + 2][r] = xv.z; sXT[k0 + 3][r] = xv.w;
        float4 yv = *(const float4*)&YA[(C0 + r) * D + k0];
        sYT[k0 + 0][r] = yv.x; sYT[k0 + 1][r] = yv.y;
        sYT[k0 + 2][r] = yv.z; sYT[k0 + 3][r] = yv.w;
    }
    __syncthreads();
    float acc[4][4];
#pragma unroll
    for (int i = 0; i < 4; ++i)
#pragma unroll
        for (int j = 0; j < 4; ++j) acc[i][j] = 0.f;
    for (int k = 0; k < 64; ++k) {
        float a[4], b[4];
        *(float4*)a = *(const float4*)&sXT[k][tr * 4];
        *(float4*)b = *(const float4*)&sYT[k][tc * 4];
#pragma unroll
        for (int i = 0; i < 4; ++i)
#pragma unroll
            for (int j = 0; j < 4; ++j)
                acc[i][j] = fmaf(a[i], b[j], acc[i][j]);
    }
    float xn[4], yn[4];
#pragma unroll
    for (int i = 0; i < 4; ++i) xn[i] = n2x[R0 + tr * 4 + i];
#pragma unroll
    for (int j = 0; j < 4; ++j) yn[j] = n2y[C0 + tc * 4 + j];
#pragma unroll
    for (int i = 0; i < 4; ++i) {
        float o[4];
#pragma unroll
        for (int j = 0; j < 4; ++j)
            o[j] = __expf(2.f * acc[i][j] - xn[i] - yn[j]);
        *(float4*)&out[(size_t)(R0 + tr * 4 + i) * N + C0 + tc * 4] = *(float4*)o;
    }
}

// ---------------------------------------------------------------------------
extern "C" void kernel_launch(void* const* d_in, const int* in_sizes, int n_in,
                              void* d_out, int out_size, void* d_ws, size_t ws_size,
                              hipStream_t stream) {
    const float* Wq = (const float*)d_in[0];   // rotation_params [64,64]
    const float* Wk = (const float*)d_in[1];   // entangle_params [64,64]
    const float* x  = (const float*)d_in[2];   // [8192,64]
    const float* y  = (const float*)d_in[3];   // [8192,64]
    float* out = (float*)d_out;                // [8192,8192]

    // workspace layout (~12.7 MB)
    float* Qx = (float*)d_ws;
    float* Kx = Qx + (size_t)N * D;
    float* Qy = Kx + (size_t)N * D;
    float* Ky = Qy + (size_t)N * D;
    float* xa = Ky + (size_t)N * D;
    float* ya = xa + (size_t)N * D;
    float* x2 = ya + (size_t)N * D;
    float* y2 = x2 + N;

    proj_kernel<<<dim3(2 * N / 16), 256, 0, stream>>>(Wq, Wk, x, y, Qx, Kx, Qy, Ky);
    attn_kernel<<<dim3(N / 64, 2), 256, 0, stream>>>(Qx, Kx, Qy, Ky, x, y,
                                                     xa, ya, x2, y2);
    rbf_kernel<<<dim3(N / 64, N / 64), 256, 0, stream>>>(xa, ya, x2, y2, out);
}

// Round 2
// 624.875 us; speedup vs baseline: 1.7103x; 1.7103x over previous
//
#include <hip/hip_runtime.h>
#include <math.h>

#define N 8192
#define D 64
#define KSPLIT 4

typedef _Float16 half_t;
typedef _Float16 f16x8 __attribute__((ext_vector_type(8)));
typedef _Float16 f16x4 __attribute__((ext_vector_type(4)));
typedef float f32x4 __attribute__((ext_vector_type(4)));

#define MFMA(a, b, c) __builtin_amdgcn_mfma_f32_16x16x32_f16((a), (b), (c), 0, 0, 0)

// split a f32 into f16 hi + f16 lo (v ~= hi + lo, rel err ~2^-22)
#define SPLIT(v, H, L) { half_t _h = (half_t)(v); (H) = _h; (L) = (half_t)((v) - (float)_h); }

// ---------------------------------------------------------------------------
// K1: Q = (X@Wq)*0.125 (f32), K = X@Wk as f16 hi/lo. 16 rows/block.
// ---------------------------------------------------------------------------
__global__ __launch_bounds__(256) void proj_kernel(
    const float* __restrict__ Wq, const float* __restrict__ Wk,
    const float* __restrict__ X, const float* __restrict__ Y,
    float* __restrict__ Qx, float* __restrict__ Qy,
    half_t* __restrict__ Khix, half_t* __restrict__ Klox,
    half_t* __restrict__ Khiy, half_t* __restrict__ Kloy)
{
    __shared__ float sWq[64][64];
    __shared__ float sWk[64][64];
    __shared__ float sIn[16][64];
    const int t = threadIdx.x;
#pragma unroll
    for (int p = 0; p < 16; ++p) {
        int idx = p * 256 + t;
        sWq[idx >> 6][idx & 63] = Wq[idx];
        sWk[idx >> 6][idx & 63] = Wk[idx];
    }
    const int R0 = blockIdx.x * 16;
    const float* src; float* dq; half_t* dkh; half_t* dkl; int r0;
    if (R0 < N) { src = X; dq = Qx; dkh = Khix; dkl = Klox; r0 = R0; }
    else        { src = Y; dq = Qy; dkh = Khiy; dkl = Kloy; r0 = R0 - N; }
#pragma unroll
    for (int p = 0; p < 4; ++p) {
        int idx = p * 256 + t;
        sIn[idx >> 6][idx & 63] = src[(size_t)r0 * D + idx];
    }
    __syncthreads();
    const int c = t & 63;
    const int rb = t >> 6;
#pragma unroll
    for (int rr = 0; rr < 4; ++rr) {
        int r = rr * 4 + rb;
        float aq = 0.f, ak = 0.f;
#pragma unroll
        for (int k = 0; k < 64; ++k) {
            float xv = sIn[r][k];
            aq = fmaf(xv, sWq[k][c], aq);
            ak = fmaf(xv, sWk[k][c], ak);
        }
        dq[(size_t)(r0 + r) * D + c] = aq * 0.125f;  // 1/sqrt(64) folded into Q
        half_t hh = (half_t)ak;
        dkh[(size_t)(r0 + r) * D + c] = hh;
        dkl[(size_t)(r0 + r) * D + c] = (half_t)(ak - (float)hh);
    }
}

// ---------------------------------------------------------------------------
// K2: zt prep: zt[d][row] = f16 hi/lo of input[row][d] (transposed, split).
// grid (128, 2), 64 rows per block.
// ---------------------------------------------------------------------------
__global__ __launch_bounds__(256) void ztprep_kernel(
    const float* __restrict__ X, const float* __restrict__ Y,
    half_t* __restrict__ zthix, half_t* __restrict__ ztlox,
    half_t* __restrict__ zthiy, half_t* __restrict__ ztloy)
{
    __shared__ float T[64][68];   // [d][r]
    const int t = threadIdx.x;
    const float* src = blockIdx.y ? Y : X;
    half_t* dh = blockIdx.y ? zthiy : zthix;
    half_t* dl = blockIdx.y ? ztloy : ztlox;
    const int r0 = blockIdx.x * 64;
#pragma unroll
    for (int p = 0; p < 4; ++p) {
        int r = p * 16 + (t >> 4);
        int c4 = (t & 15) * 4;
        f32x4 v = *(const f32x4*)&src[(size_t)(r0 + r) * D + c4];
        T[c4 + 0][r] = v[0]; T[c4 + 1][r] = v[1];
        T[c4 + 2][r] = v[2]; T[c4 + 3][r] = v[3];
    }
    __syncthreads();
    const int d = t >> 2, cb = (t & 3) * 16;
    f16x8 h0, h1, l0, l1;
#pragma unroll
    for (int i = 0; i < 8; ++i) { float v = T[d][cb + i];     SPLIT(v, h0[i], l0[i]); }
#pragma unroll
    for (int i = 0; i < 8; ++i) { float v = T[d][cb + 8 + i]; SPLIT(v, h1[i], l1[i]); }
    *(f16x8*)&dh[(size_t)d * N + r0 + cb]     = h0;
    *(f16x8*)&dh[(size_t)d * N + r0 + cb + 8] = h1;
    *(f16x8*)&dl[(size_t)d * N + r0 + cb]     = l0;
    *(f16x8*)&dl[(size_t)d * N + r0 + cb + 8] = l1;
}

// ---------------------------------------------------------------------------
// K3: flash attention via MFMA (f16 3-product split). Block = 4 waves x 32 q.
// S^T = K·Q^T (C-layout rows = kv -> cheap softmax), P via per-wave LDS,
// O^T = ZT·P. K/ZT frags straight from global (L2). KV-split -> partials.
// grid (64, 2 sides, KSPLIT). No __syncthreads anywhere.
// ---------------------------------------------------------------------------
__global__ __launch_bounds__(256, 2) void attn_kernel(
    const float* __restrict__ Qx, const float* __restrict__ Qy,
    const half_t* __restrict__ Khix, const half_t* __restrict__ Klox,
    const half_t* __restrict__ Khiy, const half_t* __restrict__ Kloy,
    const half_t* __restrict__ zthix, const half_t* __restrict__ ztlox,
    const half_t* __restrict__ zthiy, const half_t* __restrict__ ztloy,
    float* __restrict__ Opart, float* __restrict__ mpart, float* __restrict__ lpart)
{
    const int side = blockIdx.y;
    const float*  Q   = side ? Qy    : Qx;
    const half_t* Khi = side ? Khiy  : Khix;
    const half_t* Klo = side ? Kloy  : Klox;
    const half_t* Zhi = side ? zthiy : zthix;
    const half_t* Zlo = side ? ztloy : ztlox;
    const int t = threadIdx.x, w = t >> 6, lane = t & 63;
    const int c16 = lane & 15, quad = lane >> 4;
    const int q0 = blockIdx.x * 128 + w * 32;
    const int sp = blockIdx.z;
    const int kvbase = sp * (N / KSPLIT);

    __shared__ half_t Pbuf[4][2][32][40];   // [wave][hi/lo][q][kv(+pad)]
    half_t (*Phi)[40] = Pbuf[w][0];
    half_t (*Plo)[40] = Pbuf[w][1];

    // Q fragments (B-operand: lane&15 = q, k = quad*8+j), f32 -> hi/lo in regs
    f16x8 qh[2][2], ql[2][2];   // [qg][ks]
#pragma unroll
    for (int qg = 0; qg < 2; ++qg)
#pragma unroll
        for (int ks = 0; ks < 2; ++ks) {
            const float* s = &Q[(size_t)(q0 + 16 * qg + c16) * D + ks * 32 + quad * 8];
            f32x4 v0 = *(const f32x4*)s;
            f32x4 v1 = *(const f32x4*)(s + 4);
            f16x8 h, l;
#pragma unroll
            for (int i = 0; i < 4; ++i) { SPLIT(v0[i], h[i],     l[i]); }
#pragma unroll
            for (int i = 0; i < 4; ++i) { SPLIT(v1[i], h[4 + i], l[4 + i]); }
            qh[qg][ks] = h; ql[qg][ks] = l;
        }

    f32x4 ot[4][2] = {};                      // O^T accs [dt][qg]
    float m_run[2] = {-INFINITY, -INFINITY};
    float l_run[2] = {0.f, 0.f};

    for (int tt = 0; tt < (N / KSPLIT) / 32; ++tt) {
        const int kv0 = kvbase + tt * 32;
        f32x4 st[2][2] = {};                  // S^T accs [qg][tau]
#pragma unroll
        for (int ks = 0; ks < 2; ++ks)
#pragma unroll
            for (int tau = 0; tau < 2; ++tau) {
                size_t ko = (size_t)(kv0 + 16 * tau + c16) * D + ks * 32 + quad * 8;
                f16x8 kh = *(const f16x8*)&Khi[ko];
                f16x8 kl = *(const f16x8*)&Klo[ko];
#pragma unroll
                for (int qg = 0; qg < 2; ++qg) {
                    st[qg][tau] = MFMA(kh, qh[qg][ks], st[qg][tau]);
                    st[qg][tau] = MFMA(kh, ql[qg][ks], st[qg][tau]);
                    st[qg][tau] = MFMA(kl, qh[qg][ks], st[qg][tau]);
                }
            }
        // online softmax; S^T rows are kv: per-q reduce = in-lane + xor16/32
#pragma unroll
        for (int qg = 0; qg < 2; ++qg) {
            float mt = fmaxf(fmaxf(fmaxf(st[qg][0][0], st[qg][0][1]),
                                   fmaxf(st[qg][0][2], st[qg][0][3])),
                             fmaxf(fmaxf(st[qg][1][0], st[qg][1][1]),
                                   fmaxf(st[qg][1][2], st[qg][1][3])));
            mt = fmaxf(mt, __shfl_xor(mt, 16));
            mt = fmaxf(mt, __shfl_xor(mt, 32));
            float mn = fmaxf(m_run[qg], mt);
            float al = __expf(m_run[qg] - mn);
            m_run[qg] = mn;
            float ss = 0.f;
#pragma unroll
            for (int tau = 0; tau < 2; ++tau)
#pragma unroll
                for (int r = 0; r < 4; ++r) {
                    float e = __expf(st[qg][tau][r] - mn);
                    st[qg][tau][r] = e; ss += e;
                }
            ss += __shfl_xor(ss, 16);
            ss += __shfl_xor(ss, 32);
            l_run[qg] = l_run[qg] * al + ss;
#pragma unroll
            for (int dt = 0; dt < 4; ++dt) ot[dt][qg] *= al;
            // P -> LDS as f16 hi/lo, rows = q, kv contiguous (b64 stores)
#pragma unroll
            for (int tau = 0; tau < 2; ++tau) {
                f16x4 ph, pl;
#pragma unroll
                for (int r = 0; r < 4; ++r) { SPLIT(st[qg][tau][r], ph[r], pl[r]); }
                *(f16x4*)&Phi[16 * qg + c16][16 * tau + 4 * quad] = ph;
                *(f16x4*)&Plo[16 * qg + c16][16 * tau + 4 * quad] = pl;
            }
        }
        // PV: O^T[d][q] += ZT[d][kv] * P[kv][q]
        f16x8 pbh[2], pbl[2];
#pragma unroll
        for (int qg = 0; qg < 2; ++qg) {
            pbh[qg] = *(const f16x8*)&Phi[16 * qg + c16][quad * 8];
            pbl[qg] = *(const f16x8*)&Plo[16 * qg + c16][quad * 8];
        }
#pragma unroll
        for (int dt = 0; dt < 4; ++dt) {
            size_t zo = (size_t)(16 * dt + c16) * N + kv0 + quad * 8;
            f16x8 zh = *(const f16x8*)&Zhi[zo];
            f16x8 zl = *(const f16x8*)&Zlo[zo];
#pragma unroll
            for (int qg = 0; qg < 2; ++qg) {
                ot[dt][qg] = MFMA(zh, pbh[qg], ot[dt][qg]);
                ot[dt][qg] = MFMA(zh, pbl[qg], ot[dt][qg]);
                ot[dt][qg] = MFMA(zl, pbh[qg], ot[dt][qg]);
            }
        }
    }
    // epilogue: unnormalized O (relative to m_run) + m, l partials
    const size_t obase = (size_t)(side * KSPLIT + sp) * N;
#pragma unroll
    for (int qg = 0; qg < 2; ++qg) {
        int q = q0 + 16 * qg + c16;
#pragma unroll
        for (int dt = 0; dt < 4; ++dt)
#pragma unroll
            for (int r = 0; r < 4; ++r)
                Opart[(obase + q) * D + 16 * dt + 4 * quad + r] = ot[dt][qg][r];
        if (quad == 0) {
            mpart[obase + q] = m_run[qg];
            lpart[obase + q] = l_run[qg];
        }
    }
}

// ---------------------------------------------------------------------------
// K4: combine split-K partials -> xa/ya (f16 hi/lo) + squared row norms.
// grid (512, 2); thread = (q within 16, d4).
// ---------------------------------------------------------------------------
__global__ __launch_bounds__(256) void combine_kernel(
    const float* __restrict__ Opart, const float* __restrict__ mpart,
    const float* __restrict__ lpart,
    half_t* __restrict__ xahi, half_t* __restrict__ xalo,
    half_t* __restrict__ yahi, half_t* __restrict__ yalo,
    float* __restrict__ n2x, float* __restrict__ n2y)
{
    const int side = blockIdx.y;
    const int q = blockIdx.x * 16 + (threadIdx.x >> 4);
    const int d4 = (threadIdx.x & 15) * 4;
    float m[KSPLIT], l[KSPLIT];
#pragma unroll
    for (int s = 0; s < KSPLIT; ++s) {
        size_t b = (size_t)(side * KSPLIT + s) * N + q;
        m[s] = mpart[b]; l[s] = lpart[b];
    }
    float M = fmaxf(fmaxf(m[0], m[1]), fmaxf(m[2], m[3]));
    float L = 0.f;
    f32x4 o = {0.f, 0.f, 0.f, 0.f};
#pragma unroll
    for (int s = 0; s < KSPLIT; ++s) {
        float sc = __expf(m[s] - M);
        L += l[s] * sc;
        f32x4 p = *(const f32x4*)&Opart[((size_t)(side * KSPLIT + s) * N + q) * D + d4];
        o += p * sc;
    }
    float inv = 1.f / L;
    o *= inv;
    float sq = o[0] * o[0] + o[1] * o[1] + o[2] * o[2] + o[3] * o[3];
#pragma unroll
    for (int off = 1; off < 16; off <<= 1) sq += __shfl_xor(sq, off);
    half_t* dh = side ? yahi : xahi;
    half_t* dl = side ? yalo : xalo;
    float*  n2 = side ? n2y  : n2x;
    if ((threadIdx.x & 15) == 0) n2[q] = sq;
    f16x4 h4, l4;
#pragma unroll
    for (int i = 0; i < 4; ++i) { SPLIT(o[i], h4[i], l4[i]); }
    *(f16x4*)&dh[(size_t)q * D + d4] = h4;
    *(f16x4*)&dl[(size_t)q * D + d4] = l4;
}

// ---------------------------------------------------------------------------
// K5: RBF via MFMA, frags straight from global (L2). Block = 4 waves (2x2),
// 128x128 out tile, 64x64 per wave. out = exp(2*dot - |xa|^2 - |ya|^2).
// ---------------------------------------------------------------------------
__global__ __launch_bounds__(256, 2) void rbf_kernel(
    const half_t* __restrict__ xahi, const half_t* __restrict__ xalo,
    const half_t* __restrict__ yahi, const half_t* __restrict__ yalo,
    const float* __restrict__ n2x, const float* __restrict__ n2y,
    float* __restrict__ out)
{
    const int t = threadIdx.x, w = t >> 6, lane = t & 63;
    const int c16 = lane & 15, quad = lane >> 4;
    const int X0 = blockIdx.y * 128 + (w >> 1) * 64;
    const int Y0 = blockIdx.x * 128 + (w & 1) * 64;
    f32x4 acc[4][4] = {};   // [xt][yt]
#pragma unroll
    for (int ks = 0; ks < 2; ++ks) {
        f16x8 bh[4], bl[4];
#pragma unroll
        for (int yt = 0; yt < 4; ++yt) {
            size_t off = (size_t)(Y0 + 16 * yt + c16) * D + ks * 32 + quad * 8;
            bh[yt] = *(const f16x8*)&yahi[off];
            bl[yt] = *(const f16x8*)&yalo[off];
        }
#pragma unroll
        for (int xt = 0; xt < 4; ++xt) {
            size_t ao = (size_t)(X0 + 16 * xt + c16) * D + ks * 32 + quad * 8;
            f16x8 ah = *(const f16x8*)&xahi[ao];
            f16x8 al = *(const f16x8*)&xalo[ao];
#pragma unroll
            for (int yt = 0; yt < 4; ++yt) {
                acc[xt][yt] = MFMA(ah, bh[yt], acc[xt][yt]);
                acc[xt][yt] = MFMA(ah, bl[yt], acc[xt][yt]);
                acc[xt][yt] = MFMA(al, bh[yt], acc[xt][yt]);
            }
        }
    }
    float ny[4];
#pragma unroll
    for (int yt = 0; yt < 4; ++yt) ny[yt] = n2y[Y0 + 16 * yt + c16];
#pragma unroll
    for (int xt = 0; xt < 4; ++xt)
#pragma unroll
        for (int r = 0; r < 4; ++r) {
            int xr = X0 + 16 * xt + 4 * quad + r;
            float nx = n2x[xr];
#pragma unroll
            for (int yt = 0; yt < 4; ++yt) {
                float v = __expf(2.f * acc[xt][yt][r] - nx - ny[yt]);
                out[(size_t)xr * N + Y0 + 16 * yt + c16] = v;
            }
        }
}

// ---------------------------------------------------------------------------
extern "C" void kernel_launch(void* const* d_in, const int* in_sizes, int n_in,
                              void* d_out, int out_size, void* d_ws, size_t ws_size,
                              hipStream_t stream) {
    const float* Wq = (const float*)d_in[0];
    const float* Wk = (const float*)d_in[1];
    const float* x  = (const float*)d_in[2];
    const float* y  = (const float*)d_in[3];
    float* out = (float*)d_out;

    char* p = (char*)d_ws;
    auto alloc = [&](size_t bytes) -> void* {
        void* r = (void*)p;
        p += (bytes + 255) & ~(size_t)255;
        return r;
    };
    float*  Qx    = (float*) alloc((size_t)N * D * 4);
    float*  Qy    = (float*) alloc((size_t)N * D * 4);
    half_t* Khix  = (half_t*)alloc((size_t)N * D * 2);
    half_t* Klox  = (half_t*)alloc((size_t)N * D * 2);
    half_t* Khiy  = (half_t*)alloc((size_t)N * D * 2);
    half_t* Kloy  = (half_t*)alloc((size_t)N * D * 2);
    half_t* zthix = (half_t*)alloc((size_t)N * D * 2);
    half_t* ztlox = (half_t*)alloc((size_t)N * D * 2);
    half_t* zthiy = (half_t*)alloc((size_t)N * D * 2);
    half_t* ztloy = (half_t*)alloc((size_t)N * D * 2);
    float*  Opart = (float*) alloc((size_t)2 * KSPLIT * N * D * 4);
    float*  mpart = (float*) alloc((size_t)2 * KSPLIT * N * 4);
    float*  lpart = (float*) alloc((size_t)2 * KSPLIT * N * 4);
    half_t* xahi  = (half_t*)alloc((size_t)N * D * 2);
    half_t* xalo  = (half_t*)alloc((size_t)N * D * 2);
    half_t* yahi  = (half_t*)alloc((size_t)N * D * 2);
    half_t* yalo  = (half_t*)alloc((size_t)N * D * 2);
    float*  n2x   = (float*) alloc((size_t)N * 4);
    float*  n2y   = (float*) alloc((size_t)N * 4);

    proj_kernel<<<dim3(2 * N / 16), 256, 0, stream>>>(Wq, Wk, x, y, Qx, Qy,
                                                      Khix, Klox, Khiy, Kloy);
    ztprep_kernel<<<dim3(N / 64, 2), 256, 0, stream>>>(x, y, zthix, ztlox, zthiy, ztloy);
    attn_kernel<<<dim3(N / 128, 2, KSPLIT), 256, 0, stream>>>(
        Qx, Qy, Khix, Klox, Khiy, Kloy, zthix, ztlox, zthiy, ztloy,
        Opart, mpart, lpart);
    combine_kernel<<<dim3(N / 16, 2), 256, 0, stream>>>(
        Opart, mpart, lpart, xahi, xalo, yahi, yalo, n2x, n2y);
    rbf_kernel<<<dim3(N / 128, N / 128), 256, 0, stream>>>(
        xahi, xalo, yahi, yalo, n2x, n2y, out);
}